// Round 10
// baseline (867.627 us; speedup 1.0000x reference)
//
#include <hip/hip_runtime.h>
#include <math.h>

#define BB   64
#define CC   1024
#define HWC  144
#define KK   8192
#define MM   9216
#define NBN  128                 // 64-code partial-softmax blocks
#define CAP  2000000             // candidate list capacity
#define THR  1e-9f               // candidate threshold on approx code value

typedef __attribute__((ext_vector_type(8)))  short          bf16x8;
typedef __attribute__((ext_vector_type(8)))  unsigned short u16x8;
typedef __attribute__((ext_vector_type(4)))  unsigned short u16x4;
typedef __attribute__((ext_vector_type(4)))  float          f32x4;
typedef __attribute__((ext_vector_type(16))) float          f32x16;

// ws byte layout
#define OFF_FA    0                                   // 9216*1024*2 (hi only)
#define OFF_FB    (OFF_FA + (size_t)MM * CC * 2)      // 8192*1024*2
#define OFF_ESQ   (OFF_FB + (size_t)KK * CC * 2)
#define OFF_PM    (OFF_ESQ + (size_t)KK * 4)
#define OFF_PS    (OFF_PM + (size_t)NBN * MM * 4)
#define OFF_FACT  (OFF_PS + (size_t)NBN * MM * 4)
#define OFF_MA    (OFF_FACT + (size_t)NBN * MM * 4)
#define OFF_SA    (OFF_MA + (size_t)MM * 4)
#define OFF_SSUB  (OFF_SA + (size_t)MM * 4)
#define OFF_M2U   (OFF_SSUB + (size_t)MM * 4)
#define OFF_SCAND (OFF_M2U + (size_t)MM * 4)
#define OFF_ISTOT (OFF_SCAND + (size_t)MM * 4)
#define OFF_CNT   (OFF_ISTOT + (size_t)MM * 4)
#define OFF_CPOS  (OFF_CNT + 64)
#define OFF_CL2   (OFF_CPOS + (size_t)CAP * 4)
#define OFF_E     (OFF_CL2 + (size_t)CAP * 4)         // bf16 E: 151 MB

__device__ inline unsigned short f2bf(float x) {
    union { float f; unsigned u; } v; v.f = x;
    unsigned r = v.u + 0x7fffu + ((v.u >> 16) & 1u);
    return (unsigned short)(r >> 16);
}
__device__ inline float bf2f(unsigned short h) {
    union { unsigned u; float f; } v; v.u = (unsigned)h << 16;
    return v.f;
}
// order-preserving map for signed-float atomicMax on uint
__device__ inline unsigned ordOf(float x) {
    unsigned u = __float_as_uint(x);
    return (x >= 0.f) ? (u | 0x80000000u) : ~u;
}
__device__ inline float ordToF(unsigned o) {
    return (o & 0x80000000u) ? __uint_as_float(o & 0x7fffffffu)
                             : __uint_as_float(~o);
}

// ---------------------------------------------------------------------------
// init: zero candidate machinery
__global__ void init_aux(float* S_sub, unsigned* m2u, float* Scand,
                         unsigned* cnt) {
    int i = blockIdx.x * 256 + threadIdx.x;
    if (i < MM) { S_sub[i] = 0.f; m2u[i] = 0u; Scand[i] = 0.f; }
    if (i == 0) cnt[0] = 0u;
}

// ---------------------------------------------------------------------------
// Prep A: crop + transpose + bf16 (hi only) into 256-row BK=16 sub-tiles.
// slot = (bm*64+kt)*512 + oct*256 + row  (8 bf16 of A[row][kt*16+oct*8+e])
__global__ __launch_bounds__(256)
void prep_A(const float* __restrict__ feat, u16x8* __restrict__ fA) {
    __shared__ float tile[64][145];
    int cb = blockIdx.x;      // 16 channel blocks of 64
    int b  = blockIdx.y;
    for (int idx = threadIdx.x; idx < 64 * 144; idx += 256) {
        int r = idx / 144, hw = idx - r * 144;
        int h = hw / 12, w = hw - h * 12;
        tile[r][hw] = feat[(size_t)((b * 1024 + cb * 64 + r) * 196)
                           + (h + 1) * 14 + (w + 1)];
    }
    __syncthreads();
    for (int idx = threadIdx.x; idx < 8 * 144; idx += 256) {
        int g = idx / 144, hw = idx - g * 144;
        int p = b * 144 + hw;
        int bm = p >> 8, row = p & 255;
        int c = cb * 64 + g * 8;
        int kt = c >> 4, oct = (c >> 3) & 1;
        u16x8 hi;
#pragma unroll
        for (int e = 0; e < 8; ++e) hi[e] = f2bf(tile[g * 8 + e][hw]);
        fA[((size_t)bm * 64 + kt) * 512 + oct * 256 + row] = hi;
    }
}

// Prep B: 128-col tiles, hi only. slot = (nb*64+kt)*256 + oct*128 + col
__global__ __launch_bounds__(256)
void prep_B(const float* __restrict__ emb, u16x8* __restrict__ fB) {
    __shared__ float tile[128][65];
    int cb = blockIdx.x;      // 16 channel blocks of 64
    int nb = blockIdx.y;      // 64 n blocks of 128
#pragma unroll
    for (int i = 0; i < 8; ++i) {
        int idx = threadIdx.x + i * 256;
        int nl = idx >> 4, c4 = idx & 15;
        const float4 v = *reinterpret_cast<const float4*>(
            emb + (size_t)(nb * 128 + nl) * 1024 + cb * 64 + c4 * 4);
        tile[nl][c4 * 4 + 0] = v.x;
        tile[nl][c4 * 4 + 1] = v.y;
        tile[nl][c4 * 4 + 2] = v.z;
        tile[nl][c4 * 4 + 3] = v.w;
    }
    __syncthreads();
#pragma unroll
    for (int i = 0; i < 4; ++i) {
        int idx = threadIdx.x + i * 256;
        int kc = idx >> 7, rl = idx & 127;
        int c = cb * 64 + kc * 8;
        int kt = c >> 4, oct = (c >> 3) & 1;
        u16x8 hi;
#pragma unroll
        for (int e = 0; e < 8; ++e) hi[e] = f2bf(tile[rl][kc * 8 + e]);
        fB[((size_t)nb * 64 + kt) * 256 + oct * 128 + rl] = hi;
    }
}

// Row sum-of-squares for embedding (fp32 exact)
__global__ void rowsumsq(const float* __restrict__ src, float* __restrict__ dst) {
    int row = blockIdx.x * 4 + (threadIdx.x >> 6);
    int l = threadIdx.x & 63;
    const float4* p = reinterpret_cast<const float4*>(src + (size_t)row * 1024);
    float s = 0.f;
#pragma unroll
    for (int it = 0; it < 4; ++it) {
        float4 v = p[l + it * 64];
        s += v.x * v.x + v.y * v.y + v.z * v.z + v.w * v.w;
    }
#pragma unroll
    for (int off = 32; off; off >>= 1) s += __shfl_down(s, off);
    if (l == 0) dst[row] = s;
}

// ---------------------------------------------------------------------------
// Single-bf16 256x128 MFMA GEMM (hi*hi only) + fused partial softmax.
// 4 waves (2x2), wave = 128x64 (4x2 32x32x16 frags, acc 128 VGPR).
// BK=32, 2x24KB LDS dbuf -> 2 blocks/CU, counted vmcnt(6).
__global__ __launch_bounds__(256, 2)
void gemm1(const char* __restrict__ fA, const char* __restrict__ fB,
           const float* __restrict__ esq, const float* __restrict__ mdm,
           float* __restrict__ pm, float* __restrict__ ps,
           unsigned short* __restrict__ Ebf) {
    __shared__ __align__(16) char smem[49152];

    int flat = blockIdx.x;                    // 2304 = 8 * 288
    int swz = (flat & 7) * 288 + (flat >> 3); // XCD-aware, bijective
    int bm = swz >> 6, bn = swz & 63;         // 36 x 64

    int tid = threadIdx.x;
    int l = tid & 63, l31 = l & 31, lc2 = l >> 5;
    int wv = tid >> 6, wr = wv >> 1, wc = wv & 1;

    const char* gA = fA + (size_t)bm * 524288;   // 64 kt * 8 KB
    const char* gB = fB + (size_t)bn * 262144;   // 64 kt * 4 KB

    f32x16 acc[4][2];
#pragma unroll
    for (int i = 0; i < 4; ++i)
#pragma unroll
        for (int j = 0; j < 2; ++j)
#pragma unroll
            for (int r = 0; r < 16; ++r) acc[i][j][r] = 0.f;

    auto stage = [&](int buf, int t) {
        int ts = t > 31 ? 31 : t;
        char* db = smem + buf * 24576;
        const char* ga = gA + (size_t)ts * 16384;   // 2 kt of 8 KB
        const char* gb = gB + (size_t)ts * 8192;    // 2 kt of 4 KB
#pragma unroll
        for (int c = 0; c < 4; ++c) {
            __builtin_amdgcn_global_load_lds(
                (const __attribute__((address_space(1))) void*)(ga + c * 4096 + tid * 16),
                (__attribute__((address_space(3))) void*)(db + c * 4096 + tid * 16), 16, 0, 0);
        }
#pragma unroll
        for (int c = 0; c < 2; ++c) {
            __builtin_amdgcn_global_load_lds(
                (const __attribute__((address_space(1))) void*)(gb + c * 4096 + tid * 16),
                (__attribute__((address_space(3))) void*)(db + 16384 + c * 4096 + tid * 16), 16, 0, 0);
        }
    };

    stage(0, 0);
    stage(1, 1);                 // 12 loads/thread outstanding

    for (int t = 0; t < 32; ++t) {
        asm volatile("s_waitcnt vmcnt(6)" ::: "memory");
        __builtin_amdgcn_s_barrier();
        __builtin_amdgcn_sched_barrier(0);

        const char* bufc = smem + (t & 1) * 24576;
#pragma unroll
        for (int kt2 = 0; kt2 < 2; ++kt2) {
            bf16x8 ah[4], bh[2];
#pragma unroll
            for (int f = 0; f < 4; ++f)
                ah[f] = *(const bf16x8*)(bufc + kt2 * 8192 + lc2 * 4096
                                         + (wr * 128 + f * 32 + l31) * 16);
#pragma unroll
            for (int f = 0; f < 2; ++f)
                bh[f] = *(const bf16x8*)(bufc + 16384 + kt2 * 4096 + lc2 * 2048
                                         + (wc * 64 + f * 32 + l31) * 16);
            __builtin_amdgcn_s_setprio(1);
#pragma unroll
            for (int fi = 0; fi < 4; ++fi)
#pragma unroll
                for (int fj = 0; fj < 2; ++fj)
                    acc[fi][fj] = __builtin_amdgcn_mfma_f32_32x32x16_bf16(
                        ah[fi], bh[fj], acc[fi][fj], 0, 0, 0);
            __builtin_amdgcn_s_setprio(0);
        }
        __builtin_amdgcn_s_barrier();
        stage(t & 1, t + 2);
    }

    // ---- fused partial-softmax epilogue (base-2), per-wave 64 cols ----
    float invl2 = (15.0f / mdm[0]) * 1.44269504089f;
    float s2 = 2.0f * invl2;
    float e2[2];
#pragma unroll
    for (int fj = 0; fj < 2; ++fj)
        e2[fj] = invl2 * esq[bn * 128 + wc * 64 + fj * 32 + l31];

    int bnp = bn * 2 + wc;

#pragma unroll
    for (int fi = 0; fi < 4; ++fi) {
        float mx[16], ss[16];
#pragma unroll
        for (int fj = 0; fj < 2; ++fj)
#pragma unroll
            for (int r = 0; r < 16; ++r)
                acc[fi][fj][r] = s2 * acc[fi][fj][r] - e2[fj];
#pragma unroll
        for (int r = 0; r < 16; ++r)
            mx[r] = fmaxf(acc[fi][0][r], acc[fi][1][r]);
#pragma unroll
        for (int off = 1; off < 32; off <<= 1)
#pragma unroll
            for (int r = 0; r < 16; ++r)
                mx[r] = fmaxf(mx[r], __shfl_xor(mx[r], off));
#pragma unroll
        for (int r = 0; r < 16; ++r) ss[r] = 0.f;
#pragma unroll
        for (int fj = 0; fj < 2; ++fj)
#pragma unroll
            for (int r = 0; r < 16; ++r) {
                float E = exp2f(acc[fi][fj][r] - mx[r]);
                acc[fi][fj][r] = E;
                ss[r] += E;
            }
#pragma unroll
        for (int off = 1; off < 32; off <<= 1)
#pragma unroll
            for (int r = 0; r < 16; ++r)
                ss[r] += __shfl_xor(ss[r], off);

        if (l31 == 0) {
#pragma unroll
            for (int r = 0; r < 16; ++r) {
                int row = wr * 128 + fi * 32 + 8 * (r >> 2) + 4 * lc2 + (r & 3);
                int p = bm * 256 + row;
                pm[(size_t)bnp * MM + p] = mx[r];
                ps[(size_t)bnp * MM + p] = ss[r];
            }
        }
#pragma unroll
        for (int fj = 0; fj < 2; ++fj) {
            int k = bn * 128 + wc * 64 + fj * 32 + l31;
#pragma unroll
            for (int q = 0; q < 4; ++q) {
                int p0 = bm * 256 + wr * 128 + fi * 32 + 8 * q + 4 * lc2;
                int b = p0 / 144, hw = p0 - b * 144;
                u16x4 v;
                v.x = f2bf(acc[fi][fj][q * 4 + 0]);
                v.y = f2bf(acc[fi][fj][q * 4 + 1]);
                v.z = f2bf(acc[fi][fj][q * 4 + 2]);
                v.w = f2bf(acc[fi][fj][q * 4 + 3]);
                __builtin_nontemporal_store(
                    v, (u16x4*)(Ebf + ((size_t)(b * 8192 + k)) * 144 + hw));
            }
        }
    }
}

// ---------------------------------------------------------------------------
// comb1: approx global max/sum per pixel + factor1
__global__ void comb1(const float* __restrict__ pm, const float* __restrict__ ps,
                      float* __restrict__ fact, float* __restrict__ m_a,
                      float* __restrict__ S_a) {
    int p = blockIdx.x * 256 + threadIdx.x;
    float m = -INFINITY;
#pragma unroll 8
    for (int bn = 0; bn < NBN; ++bn) m = fmaxf(m, pm[(size_t)bn * MM + p]);
    float S = 0.f;
#pragma unroll 8
    for (int bn = 0; bn < NBN; ++bn)
        S += ps[(size_t)bn * MM + p] * exp2f(pm[(size_t)bn * MM + p] - m);
    float is = 1.f / S;
#pragma unroll 8
    for (int bn = 0; bn < NBN; ++bn)
        fact[(size_t)bn * MM + p] = exp2f(pm[(size_t)bn * MM + p] - m) * is;
    m_a[p] = m;
    S_a[p] = S;
}

// ---------------------------------------------------------------------------
// detect: sweep E, find candidates (approx code > THR), zero their E
__global__ __launch_bounds__(256)
void detect(unsigned short* __restrict__ E, const float* __restrict__ fact,
            const float* __restrict__ pm, float* __restrict__ S_sub,
            unsigned* __restrict__ cnt, int* __restrict__ cpos) {
    int wid = threadIdx.x >> 6, l = threadIdx.x & 63;
    int r = blockIdx.x * 4 + wid;                // b*8192 + k
    int b = r >> 13, k = r & 8191;
    u16x4* Ep = (u16x4*)(E + (size_t)r * 144);
    const float* Fr = fact + (size_t)(k >> 6) * MM + b * 144;
    const float* Pr = pm + (size_t)(k >> 6) * MM + b * 144;
    if (l < 36) {
        u16x4 e = Ep[l];
        f32x4 f = *(const f32x4*)(Fr + l * 4);
        bool mod = false;
#pragma unroll
        for (int j = 0; j < 4; ++j) {
            float Ef = bf2f(e[j]);
            float v = Ef * f[j];
            if (v > THR) {
                int hw = l * 4 + j;
                int p = b * 144 + hw;
                unsigned idx = atomicAdd(cnt, 1u);
                if (idx < CAP) {
                    cpos[idx] = r * 144 + hw;
                    atomicAdd(&S_sub[p], v);
                    e[j] = 0;
                    mod = true;
                }
            }
        }
        if (mod) Ep[l] = e;
    }
}

// ---------------------------------------------------------------------------
// refine1: exact fp32 logit per candidate (one wave each); atomicMax m2
__global__ __launch_bounds__(256)
void refine1(const int* __restrict__ cpos, const unsigned* __restrict__ cnt,
             const float* __restrict__ feat, const float* __restrict__ emb,
             const float* __restrict__ esq, const float* __restrict__ mdm,
             float* __restrict__ cl2, unsigned* __restrict__ m2u) {
    int l = threadIdx.x & 63;
    int gw = blockIdx.x * 4 + (threadIdx.x >> 6);
    int nw = gridDim.x * 4;
    int n = (int)min(cnt[0], (unsigned)CAP);
    float invl2 = (15.0f / mdm[0]) * 1.44269504089f;
    for (int i = gw; i < n; i += nw) {
        int pos = cpos[i];
        int r = pos / 144, hw = pos - r * 144;
        int b = r >> 13, k = r & 8191;
        int h = hw / 12, w = hw - h * 12;
        int c0 = l * 16;
        const float* fp = feat + ((size_t)(b * 1024 + c0)) * 196
                          + (h + 1) * 14 + (w + 1);
        const float4* ep = (const float4*)(emb + (size_t)k * 1024 + c0);
        float dot = 0.f;
#pragma unroll
        for (int j4 = 0; j4 < 4; ++j4) {
            float4 ev = ep[j4];
            dot = fmaf(fp[(size_t)(j4 * 4 + 0) * 196], ev.x, dot);
            dot = fmaf(fp[(size_t)(j4 * 4 + 1) * 196], ev.y, dot);
            dot = fmaf(fp[(size_t)(j4 * 4 + 2) * 196], ev.z, dot);
            dot = fmaf(fp[(size_t)(j4 * 4 + 3) * 196], ev.w, dot);
        }
#pragma unroll
        for (int off = 32; off; off >>= 1) dot += __shfl_xor(dot, off);
        if (l == 0) {
            float l2 = invl2 * (2.f * dot - esq[k]);
            cl2[i] = l2;
            int p = b * 144 + hw;
            atomicMax(&m2u[p], ordOf(l2));
        }
    }
}

// refine2: exact candidate mass per pixel
__global__ void refine2(const int* __restrict__ cpos, const float* __restrict__ cl2,
                        const unsigned* __restrict__ cnt,
                        const unsigned* __restrict__ m2u,
                        float* __restrict__ Scand) {
    int gt = blockIdx.x * 256 + threadIdx.x;
    int nt = gridDim.x * 256;
    int n = (int)min(cnt[0], (unsigned)CAP);
    for (int i = gt; i < n; i += nt) {
        int pos = cpos[i];
        int r = pos / 144, hw = pos - r * 144;
        int p = (r >> 13) * 144 + hw;
        atomicAdd(&Scand[p], exp2f(cl2[i] - ordToF(m2u[p])));
    }
}

// ---------------------------------------------------------------------------
// comb2: corrected denominator; rewrite factor; per-pixel 1/Stot
__global__ void comb2(const float* __restrict__ pm, const float* __restrict__ m_a,
                      const float* __restrict__ S_a, const float* __restrict__ S_sub,
                      const unsigned* __restrict__ m2u, const float* __restrict__ Scand,
                      float* __restrict__ fact, float* __restrict__ iStot) {
    int p = blockIdx.x * 256 + threadIdx.x;
    float m2 = ordToF(m2u[p]);
    float Snc = S_a[p] * fmaxf(1.f - S_sub[p], 0.f);
    float Stot = Snc * exp2f(m_a[p] - m2) + Scand[p];
    float inv = 1.f / Stot;
    iStot[p] = inv;
#pragma unroll 8
    for (int bn = 0; bn < NBN; ++bn)
        fact[(size_t)bn * MM + p] = exp2f(pm[(size_t)bn * MM + p] - m2) * inv;
}

// ---------------------------------------------------------------------------
// scale_bow: codes = E(bf16) * fact -> f32, bow[r] = row max
__global__ __launch_bounds__(256)
void scale_bow(const unsigned short* __restrict__ E, const float* __restrict__ fact,
               float* __restrict__ codes, float* __restrict__ bow) {
    int wid = threadIdx.x >> 6, l = threadIdx.x & 63;
    int r = blockIdx.x * 4 + wid;
    int b = r >> 13, k = r & 8191;
    const u16x4* Ep = (const u16x4*)(E + (size_t)r * 144);
    f32x4* Cp = (f32x4*)(codes + (size_t)r * 144);
    const f32x4* Fp = (const f32x4*)(fact + (size_t)(k >> 6) * MM + b * 144);
    float m = 0.f;
    if (l < 36) {
        u16x4 e = __builtin_nontemporal_load(Ep + l);
        f32x4 f = Fp[l];
        f32x4 v;
        v.x = bf2f(e.x) * f.x;
        v.y = bf2f(e.y) * f.y;
        v.z = bf2f(e.z) * f.z;
        v.w = bf2f(e.w) * f.w;
        __builtin_nontemporal_store(v, Cp + l);
        m = fmaxf(fmaxf(v.x, v.y), fmaxf(v.z, v.w));
    }
#pragma unroll
    for (int off = 32; off; off >>= 1) m = fmaxf(m, __shfl_down(m, off));
    if (l == 0) bow[r] = m;
}

// scatter exact candidate values; fix bow via atomicMax (non-neg floats)
__global__ void scatter(const int* __restrict__ cpos, const float* __restrict__ cl2,
                        const unsigned* __restrict__ cnt,
                        const unsigned* __restrict__ m2u,
                        const float* __restrict__ iStot,
                        float* __restrict__ codes, float* __restrict__ bow) {
    int gt = blockIdx.x * 256 + threadIdx.x;
    int nt = gridDim.x * 256;
    int n = (int)min(cnt[0], (unsigned)CAP);
    for (int i = gt; i < n; i += nt) {
        int pos = cpos[i];
        int r = pos / 144, hw = pos - r * 144;
        int p = (r >> 13) * 144 + hw;
        float v = exp2f(cl2[i] - ordToF(m2u[p])) * iStot[p];
        codes[pos] = v;
        atomicMax((unsigned*)&bow[r], __float_as_uint(v));
    }
}

// L1-normalize bow per b
__global__ void bow_norm(float* __restrict__ bow) {
    __shared__ float lds[4];
    __shared__ float stot;
    int b = blockIdx.x;
    float* p = bow + b * 8192;
    float s = 0.f;
    for (int i = threadIdx.x; i < 8192; i += 256) s += fabsf(p[i]);
#pragma unroll
    for (int off = 32; off; off >>= 1) s += __shfl_down(s, off);
    int wid = threadIdx.x >> 6, l = threadIdx.x & 63;
    if (l == 0) lds[wid] = s;
    __syncthreads();
    if (threadIdx.x == 0) stot = 1.f / (lds[0] + lds[1] + lds[2] + lds[3]);
    __syncthreads();
    float inv = stot;
    for (int i = threadIdx.x; i < 8192; i += 256) p[i] *= inv;
}

// ---------------------------------------------------------------------------
extern "C" void kernel_launch(void* const* d_in, const int* in_sizes, int n_in,
                              void* d_out, int out_size, void* d_ws, size_t ws_size,
                              hipStream_t stream) {
    const float* feat = (const float*)d_in[0];
    const float* emb  = (const float*)d_in[1];
    const float* mdm  = (const float*)d_in[2];
    float* bow   = (float*)d_out;
    float* codes = (float*)d_out + (size_t)BB * KK;

    char* ws = (char*)d_ws;
    u16x8* fA     = (u16x8*)(ws + OFF_FA);
    u16x8* fB     = (u16x8*)(ws + OFF_FB);
    float* esq    = (float*)(ws + OFF_ESQ);
    float* pm     = (float*)(ws + OFF_PM);
    float* ps     = (float*)(ws + OFF_PS);
    float* fact   = (float*)(ws + OFF_FACT);
    float* m_a    = (float*)(ws + OFF_MA);
    float* S_a    = (float*)(ws + OFF_SA);
    float* S_sub  = (float*)(ws + OFF_SSUB);
    unsigned* m2u = (unsigned*)(ws + OFF_M2U);
    float* Scand  = (float*)(ws + OFF_SCAND);
    float* iStot  = (float*)(ws + OFF_ISTOT);
    unsigned* cnt = (unsigned*)(ws + OFF_CNT);
    int* cpos     = (int*)(ws + OFF_CPOS);
    float* cl2    = (float*)(ws + OFF_CL2);
    unsigned short* Ebf = (unsigned short*)(ws + OFF_E);

    init_aux<<<36, 256, 0, stream>>>(S_sub, m2u, Scand, cnt);
    prep_A<<<dim3(16, 64), 256, 0, stream>>>(feat, fA);
    prep_B<<<dim3(16, 64), 256, 0, stream>>>(emb, fB);
    rowsumsq<<<KK / 4, 256, 0, stream>>>(emb, esq);
    gemm1<<<2304, 256, 0, stream>>>((const char*)fA, (const char*)fB,
                                    esq, mdm, pm, ps, Ebf);
    comb1<<<36, 256, 0, stream>>>(pm, ps, fact, m_a, S_a);
    detect<<<(BB * KK) / 4, 256, 0, stream>>>(Ebf, fact, pm, S_sub, cnt, cpos);
    refine1<<<1024, 256, 0, stream>>>(cpos, cnt, feat, emb, esq, mdm, cl2, m2u);
    refine2<<<256, 256, 0, stream>>>(cpos, cl2, cnt, m2u, Scand);
    comb2<<<36, 256, 0, stream>>>(pm, m_a, S_a, S_sub, m2u, Scand, fact, iStot);
    scale_bow<<<(BB * KK) / 4, 256, 0, stream>>>(Ebf, fact, codes, bow);
    scatter<<<256, 256, 0, stream>>>(cpos, cl2, cnt, m2u, iStot, codes, bow);
    bow_norm<<<BB, 256, 0, stream>>>(bow);
}

// Round 11
// 601.942 us; speedup vs baseline: 1.4414x; 1.4414x over previous
//
#include <hip/hip_runtime.h>
#include <math.h>

#define BB   64
#define CC   1024
#define HWC  144
#define KK   8192
#define MM   9216
#define NBN  64                  // 128-code partial-softmax blocks
#define CAP  1000000             // candidate list capacity
#define THR  1e-9f               // candidate threshold on approx code value

typedef __attribute__((ext_vector_type(8)))  short          bf16x8;
typedef __attribute__((ext_vector_type(8)))  unsigned short u16x8;
typedef __attribute__((ext_vector_type(4)))  unsigned short u16x4;
typedef __attribute__((ext_vector_type(4)))  float          f32x4;

// ws byte layout
#define OFF_FA    0                                    // 72 bm x 32 kt x 8KB
#define OFF_FB    (OFF_FA + (size_t)72 * 32 * 8192)    // 64 bn x 32 kt x 8KB
#define OFF_ESQ   (OFF_FB + (size_t)64 * 32 * 8192)
#define OFF_PM    (OFF_ESQ + (size_t)KK * 4)
#define OFF_PS    (OFF_PM + (size_t)NBN * MM * 4)
#define OFF_FACT  (OFF_PS + (size_t)NBN * MM * 4)
#define OFF_MA    (OFF_FACT + (size_t)NBN * MM * 4)
#define OFF_SA    (OFF_MA + (size_t)MM * 4)
#define OFF_SSUB  (OFF_SA + (size_t)MM * 4)
#define OFF_M2U   (OFF_SSUB + (size_t)MM * 4)
#define OFF_SCAND (OFF_M2U + (size_t)MM * 4)
#define OFF_ISTOT (OFF_SCAND + (size_t)MM * 4)
#define OFF_CNT   (OFF_ISTOT + (size_t)MM * 4)
#define OFF_CPOS  (OFF_CNT + 64)
#define OFF_CL2   (OFF_CPOS + (size_t)CAP * 4)
#define OFF_E     (OFF_CL2 + (size_t)CAP * 4)          // bf16 E: 151 MB

__device__ inline unsigned short f2bf(float x) {
    union { float f; unsigned u; } v; v.f = x;
    unsigned r = v.u + 0x7fffu + ((v.u >> 16) & 1u);
    return (unsigned short)(r >> 16);
}
__device__ inline float bf2f(unsigned short h) {
    union { unsigned u; float f; } v; v.u = (unsigned)h << 16;
    return v.f;
}
__device__ inline unsigned ordOf(float x) {
    unsigned u = __float_as_uint(x);
    return (x >= 0.f) ? (u | 0x80000000u) : ~u;
}
__device__ inline float ordToF(unsigned o) {
    return (o & 0x80000000u) ? __uint_as_float(o & 0x7fffffffu)
                             : __uint_as_float(~o);
}

// ---------------------------------------------------------------------------
__global__ void init_aux(float* S_sub, unsigned* m2u, float* Scand,
                         unsigned* cnt) {
    int i = blockIdx.x * 256 + threadIdx.x;
    if (i < MM) { S_sub[i] = 0.f; m2u[i] = 0u; Scand[i] = 0.f; }
    if (i == 0) cnt[0] = 0u;
}

// ---------------------------------------------------------------------------
// Prep A: crop + transpose; emit (a) bf16-hi tiles for MFMA, (b) f32 fT
// (staged in the codes output region) for exact candidate refinement.
// fA slot = (bm*32+kt)*512 + chunk*128 + row : 8 bf16 of A[row][kt*32+chunk*8+e]
__global__ __launch_bounds__(256)
void prep_A(const float* __restrict__ feat, u16x8* __restrict__ fA,
            float* __restrict__ fT) {
    __shared__ float tile[64][145];
    int cb = blockIdx.x;      // 16 channel blocks of 64
    int b  = blockIdx.y;
    for (int idx = threadIdx.x; idx < 64 * 144; idx += 256) {
        int r = idx / 144, hw = idx - r * 144;
        int h = hw / 12, w = hw - h * 12;
        tile[r][hw] = feat[(size_t)((b * 1024 + cb * 64 + r) * 196)
                           + (h + 1) * 14 + (w + 1)];
    }
    __syncthreads();
    for (int idx = threadIdx.x; idx < 8 * 144; idx += 256) {
        int g = idx / 144, hw = idx - g * 144;       // hw fastest -> coalesced
        int p = b * 144 + hw;
        int bm = p >> 7, row = p & 127;
        int c = cb * 64 + g * 8;
        int kt = c >> 5, chunk = (c >> 3) & 3;
        u16x8 hi;
#pragma unroll
        for (int e = 0; e < 8; ++e) hi[e] = f2bf(tile[g * 8 + e][hw]);
        fA[((size_t)bm * 32 + kt) * 512 + chunk * 128 + row] = hi;
    }
    for (int idx = threadIdx.x; idx < 64 * 144; idx += 256) {
        int hw = idx >> 6, c0 = idx & 63;            // c0 fastest -> coalesced
        fT[(size_t)(b * 144 + hw) * 1024 + cb * 64 + c0] = tile[c0][hw];
    }
}

// Prep B: 128-col tiles, hi only, same slot layout (col = row).
__global__ __launch_bounds__(256)
void prep_B(const float* __restrict__ emb, u16x8* __restrict__ fB) {
    __shared__ float tile[128][65];
    int cb = blockIdx.x;      // 16 channel blocks of 64
    int bn = blockIdx.y;      // 64 n blocks of 128
#pragma unroll
    for (int i = 0; i < 8; ++i) {
        int idx = threadIdx.x + i * 256;             // < 2048
        int nl = idx >> 4, c4 = idx & 15;
        const float4 v = *reinterpret_cast<const float4*>(
            emb + (size_t)(bn * 128 + nl) * 1024 + cb * 64 + c4 * 4);
        tile[nl][c4 * 4 + 0] = v.x;
        tile[nl][c4 * 4 + 1] = v.y;
        tile[nl][c4 * 4 + 2] = v.z;
        tile[nl][c4 * 4 + 3] = v.w;
    }
    __syncthreads();
#pragma unroll
    for (int i = 0; i < 4; ++i) {
        int idx = threadIdx.x + i * 256;             // < 1024
        int kc = idx >> 7, rl = idx & 127;           // rl fastest -> coalesced
        int c = cb * 64 + kc * 8;
        int kt = c >> 5, chunk = (c >> 3) & 3;
        u16x8 hi;
#pragma unroll
        for (int e = 0; e < 8; ++e) hi[e] = f2bf(tile[rl][kc * 8 + e]);
        fB[((size_t)bn * 32 + kt) * 512 + chunk * 128 + rl] = hi;
    }
}

// Row sum-of-squares for embedding (fp32 exact)
__global__ void rowsumsq(const float* __restrict__ src, float* __restrict__ dst) {
    int row = blockIdx.x * 4 + (threadIdx.x >> 6);
    int l = threadIdx.x & 63;
    const float4* p = reinterpret_cast<const float4*>(src + (size_t)row * 1024);
    float s = 0.f;
#pragma unroll
    for (int it = 0; it < 4; ++it) {
        float4 v = p[l + it * 64];
        s += v.x * v.x + v.y * v.y + v.z * v.z + v.w * v.w;
    }
#pragma unroll
    for (int off = 32; off; off >>= 1) s += __shfl_down(s, off);
    if (l == 0) dst[row] = s;
}

// ---------------------------------------------------------------------------
// Hi-only 128x128 MFMA GEMM (R3-proven syncthreads-dbuf loop) + fused
// partial softmax.  4 waves (2x2 of 64x64), BK=32, 2x16KB LDS -> 3 blocks/CU.
__global__ __launch_bounds__(256, 3)
void gemm1(const char* __restrict__ fA, const char* __restrict__ fB,
           const float* __restrict__ esq, const float* __restrict__ mdm,
           float* __restrict__ pm, float* __restrict__ ps,
           unsigned short* __restrict__ Ebf) {
    __shared__ __align__(16) char smem[32768];

    int flat = blockIdx.x;                    // 4608 = 8 * 576
    int swz = (flat & 7) * 576 + (flat >> 3); // XCD-aware, bijective
    int bm = swz >> 6, bn = swz & 63;         // 72 x 64

    int tid = threadIdx.x;
    int l = tid & 63, lr = l & 15, lc = l >> 4;
    int wv = tid >> 6, wr = wv >> 1, wc = wv & 1;

    const char* gA = fA + (size_t)bm * 262144;   // 32 kt * 8 KB
    const char* gB = fB + (size_t)bn * 262144;

    f32x4 acc[4][4];
#pragma unroll
    for (int i = 0; i < 4; ++i)
#pragma unroll
        for (int j = 0; j < 4; ++j) acc[i][j] = (f32x4){0.f, 0.f, 0.f, 0.f};

    auto stage = [&](int nb, int kt) {
        char* db = smem + nb * 16384;
        const char* ga = gA + (size_t)kt * 8192;
        const char* gb = gB + (size_t)kt * 8192;
#pragma unroll
        for (int i = 0; i < 2; ++i) {
            int off = i * 4096 + tid * 16;
            __builtin_amdgcn_global_load_lds(
                (const __attribute__((address_space(1))) void*)(ga + off),
                (__attribute__((address_space(3))) void*)(db + off), 16, 0, 0);
            __builtin_amdgcn_global_load_lds(
                (const __attribute__((address_space(1))) void*)(gb + off),
                (__attribute__((address_space(3))) void*)(db + 8192 + off), 16, 0, 0);
        }
    };

    stage(0, 0);
    __syncthreads();
    int cur = 0;
    for (int kt = 0; kt < 32; ++kt) {
        if (kt < 31) stage(cur ^ 1, kt + 1);
        const char* bufc = smem + cur * 16384;
        bf16x8 ah[4], bh[4];
#pragma unroll
        for (int f = 0; f < 4; ++f) {
            int ao = (lc * 128 + wr * 64 + f * 16 + lr) * 16;
            ah[f] = *(const bf16x8*)(bufc + ao);
            int bo = (lc * 128 + wc * 64 + f * 16 + lr) * 16;
            bh[f] = *(const bf16x8*)(bufc + 8192 + bo);
        }
#pragma unroll
        for (int fi = 0; fi < 4; ++fi)
#pragma unroll
            for (int fj = 0; fj < 4; ++fj)
                acc[fi][fj] = __builtin_amdgcn_mfma_f32_16x16x32_bf16(
                    ah[fi], bh[fj], acc[fi][fj], 0, 0, 0);
        __syncthreads();
        cur ^= 1;
    }

    // ---- fused partial-softmax epilogue (base-2 domain) ----
    float invl2 = (15.0f / mdm[0]) * 1.44269504089f;
    float s2 = 2.0f * invl2;
    float e2[4];
#pragma unroll
    for (int fj = 0; fj < 4; ++fj)
        e2[fj] = invl2 * esq[bn * 128 + wc * 64 + fj * 16 + lr];

#pragma unroll
    for (int fi = 0; fi < 4; ++fi)
#pragma unroll
        for (int fj = 0; fj < 4; ++fj)
#pragma unroll
            for (int j = 0; j < 4; ++j)
                acc[fi][fj][j] = s2 * acc[fi][fj][j] - e2[fj];

    float mx[4][4];
#pragma unroll
    for (int fi = 0; fi < 4; ++fi)
#pragma unroll
        for (int j = 0; j < 4; ++j)
            mx[fi][j] = fmaxf(fmaxf(acc[fi][0][j], acc[fi][1][j]),
                              fmaxf(acc[fi][2][j], acc[fi][3][j]));
#pragma unroll
    for (int off = 1; off < 16; off <<= 1)
#pragma unroll
        for (int fi = 0; fi < 4; ++fi)
#pragma unroll
            for (int j = 0; j < 4; ++j)
                mx[fi][j] = fmaxf(mx[fi][j], __shfl_xor(mx[fi][j], off));

    float* sm = (float*)smem;     // [0..255] max[wc][128]; [256..511] sum
    if (lr == 0) {
#pragma unroll
        for (int fi = 0; fi < 4; ++fi)
#pragma unroll
            for (int j = 0; j < 4; ++j)
                sm[wc * 128 + wr * 64 + fi * 16 + lc * 4 + j] = mx[fi][j];
    }
    __syncthreads();
    float mp[4][4];
#pragma unroll
    for (int fi = 0; fi < 4; ++fi)
#pragma unroll
        for (int j = 0; j < 4; ++j) {
            int pi = wr * 64 + fi * 16 + lc * 4 + j;
            mp[fi][j] = fmaxf(sm[pi], sm[128 + pi]);
        }

    float ss[4][4];
#pragma unroll
    for (int fi = 0; fi < 4; ++fi)
#pragma unroll
        for (int j = 0; j < 4; ++j) ss[fi][j] = 0.f;
#pragma unroll
    for (int fi = 0; fi < 4; ++fi)
#pragma unroll
        for (int fj = 0; fj < 4; ++fj)
#pragma unroll
            for (int j = 0; j < 4; ++j) {
                float E = exp2f(acc[fi][fj][j] - mp[fi][j]);
                acc[fi][fj][j] = E;
                ss[fi][j] += E;
            }
#pragma unroll
    for (int off = 1; off < 16; off <<= 1)
#pragma unroll
        for (int fi = 0; fi < 4; ++fi)
#pragma unroll
            for (int j = 0; j < 4; ++j)
                ss[fi][j] += __shfl_xor(ss[fi][j], off);
    if (lr == 0) {
#pragma unroll
        for (int fi = 0; fi < 4; ++fi)
#pragma unroll
            for (int j = 0; j < 4; ++j)
                sm[256 + wc * 128 + wr * 64 + fi * 16 + lc * 4 + j] = ss[fi][j];
    }
    __syncthreads();
    if (tid < 128) {
        int p = bm * 128 + tid;
        pm[(size_t)bn * MM + p] = fmaxf(sm[tid], sm[128 + tid]);
        ps[(size_t)bn * MM + p] = sm[256 + tid] + sm[384 + tid];
    }

    // NT-store bf16 E
#pragma unroll
    for (int fi = 0; fi < 4; ++fi) {
        int p0 = bm * 128 + wr * 64 + fi * 16 + lc * 4;
        int b = p0 / 144, hw = p0 - b * 144;          // 4-run stays in b
#pragma unroll
        for (int fj = 0; fj < 4; ++fj) {
            int k = bn * 128 + wc * 64 + fj * 16 + lr;
            u16x4 v;
            v.x = f2bf(acc[fi][fj].x);
            v.y = f2bf(acc[fi][fj].y);
            v.z = f2bf(acc[fi][fj].z);
            v.w = f2bf(acc[fi][fj].w);
            __builtin_nontemporal_store(
                v, (u16x4*)(Ebf + ((size_t)(b * 8192 + k)) * 144 + hw));
        }
    }
}

// ---------------------------------------------------------------------------
// comb1: approx global max/sum per pixel + approx factor
__global__ void comb1(const float* __restrict__ pm, const float* __restrict__ ps,
                      float* __restrict__ fact, float* __restrict__ m_a,
                      float* __restrict__ S_a) {
    int p = blockIdx.x * 256 + threadIdx.x;
    float m = -INFINITY;
#pragma unroll 8
    for (int bn = 0; bn < NBN; ++bn) m = fmaxf(m, pm[(size_t)bn * MM + p]);
    float S = 0.f;
#pragma unroll 8
    for (int bn = 0; bn < NBN; ++bn)
        S += ps[(size_t)bn * MM + p] * exp2f(pm[(size_t)bn * MM + p] - m);
    float is = 1.f / S;
#pragma unroll 8
    for (int bn = 0; bn < NBN; ++bn)
        fact[(size_t)bn * MM + p] = exp2f(pm[(size_t)bn * MM + p] - m) * is;
    m_a[p] = m;
    S_a[p] = S;
}

// ---------------------------------------------------------------------------
// detect: full-lane linear sweep of E; candidates (approx code > THR) are
// zeroed in E, logged, and their approx mass accumulated.
__global__ __launch_bounds__(256)
void detect(unsigned short* __restrict__ E, const float* __restrict__ fact,
            float* __restrict__ S_sub, unsigned* __restrict__ cnt,
            int* __restrict__ cpos) {
    u16x8* Ev = (u16x8*)E;                       // 9,437,184 vecs, 18 per row
    int base = blockIdx.x * 1024;
#pragma unroll
    for (int i = 0; i < 4; ++i) {
        int v = base + i * 256 + threadIdx.x;
        u16x8 e = Ev[v];
        int r = v / 18;                          // b*8192 + k
        int hw0 = (v - r * 18) * 8;
        int b = r >> 13, k = r & 8191;
        const float* Fr = fact + (size_t)(k >> 7) * MM + b * 144 + hw0;
        bool mod = false;
#pragma unroll
        for (int j = 0; j < 8; ++j) {
            float va = bf2f(e[j]) * Fr[j];
            if (va > THR) {
                unsigned idx = atomicAdd(cnt, 1u);
                if (idx < CAP) {
                    cpos[idx] = r * 144 + hw0 + j;
                    atomicAdd(&S_sub[b * 144 + hw0 + j], va);
                    e[j] = 0;
                    mod = true;
                }
            }
        }
        if (mod) Ev[v] = e;
    }
}

// ---------------------------------------------------------------------------
// refine1: exact fp32 logit per candidate (one wave each), reading the
// coalesced fT staging; atomicMax running exact max per pixel.
__global__ __launch_bounds__(256)
void refine1(const int* __restrict__ cpos, const unsigned* __restrict__ cnt,
             const float* __restrict__ fT, const float* __restrict__ emb,
             const float* __restrict__ esq, const float* __restrict__ mdm,
             float* __restrict__ cl2, unsigned* __restrict__ m2u) {
    int l = threadIdx.x & 63;
    int gw = blockIdx.x * 4 + (threadIdx.x >> 6);
    int nw = gridDim.x * 4;
    int n = (int)min(cnt[0], (unsigned)CAP);
    float invl2 = (15.0f / mdm[0]) * 1.44269504089f;
    for (int i = gw; i < n; i += nw) {
        int pos = cpos[i];
        int r = pos / 144, hw = pos - r * 144;
        int b = r >> 13, k = r & 8191;
        int p = b * 144 + hw;
        const f32x4* fp = (const f32x4*)(fT + (size_t)p * 1024 + l * 16);
        const f32x4* ep = (const f32x4*)(emb + (size_t)k * 1024 + l * 16);
        float dot = 0.f;
#pragma unroll
        for (int j4 = 0; j4 < 4; ++j4) {
            f32x4 fv = fp[j4], ev = ep[j4];
            dot = fmaf(fv.x, ev.x, dot);
            dot = fmaf(fv.y, ev.y, dot);
            dot = fmaf(fv.z, ev.z, dot);
            dot = fmaf(fv.w, ev.w, dot);
        }
#pragma unroll
        for (int off = 32; off; off >>= 1) dot += __shfl_xor(dot, off);
        if (l == 0) {
            float l2 = invl2 * (2.f * dot - esq[k]);
            cl2[i] = l2;
            atomicMax(&m2u[p], ordOf(l2));
        }
    }
}

// refine2: exact candidate mass per pixel
__global__ void refine2(const int* __restrict__ cpos, const float* __restrict__ cl2,
                        const unsigned* __restrict__ cnt,
                        const unsigned* __restrict__ m2u,
                        float* __restrict__ Scand) {
    int gt = blockIdx.x * 256 + threadIdx.x;
    int nt = gridDim.x * 256;
    int n = (int)min(cnt[0], (unsigned)CAP);
    for (int i = gt; i < n; i += nt) {
        int pos = cpos[i];
        int r = pos / 144, hw = pos - r * 144;
        int p = (r >> 13) * 144 + hw;
        atomicAdd(&Scand[p], exp2f(cl2[i] - ordToF(m2u[p])));
    }
}

// ---------------------------------------------------------------------------
// comb2: corrected denominator; rewrite factor; per-pixel 1/Stot
__global__ void comb2(const float* __restrict__ pm, const float* __restrict__ m_a,
                      const float* __restrict__ S_a, const float* __restrict__ S_sub,
                      const unsigned* __restrict__ m2u, const float* __restrict__ Scand,
                      float* __restrict__ fact, float* __restrict__ iStot) {
    int p = blockIdx.x * 256 + threadIdx.x;
    float m2 = ordToF(m2u[p]);
    float Snc = S_a[p] * fmaxf(1.f - S_sub[p], 0.f);
    float Stot = Snc * exp2f(m_a[p] - m2) + Scand[p];
    float inv = 1.f / Stot;
    iStot[p] = inv;
#pragma unroll 8
    for (int bn = 0; bn < NBN; ++bn)
        fact[(size_t)bn * MM + p] = exp2f(pm[(size_t)bn * MM + p] - m2) * inv;
}

// ---------------------------------------------------------------------------
// scale_bow: codes = E(bf16) * fact -> f32, bow[r] = row max
__global__ __launch_bounds__(256)
void scale_bow(const unsigned short* __restrict__ E, const float* __restrict__ fact,
               float* __restrict__ codes, float* __restrict__ bow) {
    int wid = threadIdx.x >> 6, l = threadIdx.x & 63;
    int r = blockIdx.x * 4 + wid;
    int b = r >> 13, k = r & 8191;
    const u16x4* Ep = (const u16x4*)(E + (size_t)r * 144);
    f32x4* Cp = (f32x4*)(codes + (size_t)r * 144);
    const f32x4* Fp = (const f32x4*)(fact + (size_t)(k >> 7) * MM + b * 144);
    float m = 0.f;
    if (l < 36) {
        u16x4 e = __builtin_nontemporal_load(Ep + l);
        f32x4 f = Fp[l];
        f32x4 v;
        v.x = bf2f(e.x) * f.x;
        v.y = bf2f(e.y) * f.y;
        v.z = bf2f(e.z) * f.z;
        v.w = bf2f(e.w) * f.w;
        __builtin_nontemporal_store(v, Cp + l);
        m = fmaxf(fmaxf(v.x, v.y), fmaxf(v.z, v.w));
    }
#pragma unroll
    for (int off = 32; off; off >>= 1) m = fmaxf(m, __shfl_down(m, off));
    if (l == 0) bow[r] = m;
}

// scatter exact candidate values; fix bow via atomicMax (non-negative floats)
__global__ void scatter(const int* __restrict__ cpos, const float* __restrict__ cl2,
                        const unsigned* __restrict__ cnt,
                        const unsigned* __restrict__ m2u,
                        const float* __restrict__ iStot,
                        float* __restrict__ codes, float* __restrict__ bow) {
    int gt = blockIdx.x * 256 + threadIdx.x;
    int nt = gridDim.x * 256;
    int n = (int)min(cnt[0], (unsigned)CAP);
    for (int i = gt; i < n; i += nt) {
        int pos = cpos[i];
        int r = pos / 144, hw = pos - r * 144;
        int p = (r >> 13) * 144 + hw;
        float v = exp2f(cl2[i] - ordToF(m2u[p])) * iStot[p];
        codes[pos] = v;
        atomicMax((unsigned*)&bow[r], __float_as_uint(v));
    }
}

// L1-normalize bow per b
__global__ void bow_norm(float* __restrict__ bow) {
    __shared__ float lds[4];
    __shared__ float stot;
    int b = blockIdx.x;
    float* p = bow + b * 8192;
    float s = 0.f;
    for (int i = threadIdx.x; i < 8192; i += 256) s += fabsf(p[i]);
#pragma unroll
    for (int off = 32; off; off >>= 1) s += __shfl_down(s, off);
    int wid = threadIdx.x >> 6, l = threadIdx.x & 63;
    if (l == 0) lds[wid] = s;
    __syncthreads();
    if (threadIdx.x == 0) stot = 1.f / (lds[0] + lds[1] + lds[2] + lds[3]);
    __syncthreads();
    float inv = stot;
    for (int i = threadIdx.x; i < 8192; i += 256) p[i] *= inv;
}

// ---------------------------------------------------------------------------
extern "C" void kernel_launch(void* const* d_in, const int* in_sizes, int n_in,
                              void* d_out, int out_size, void* d_ws, size_t ws_size,
                              hipStream_t stream) {
    const float* feat = (const float*)d_in[0];
    const float* emb  = (const float*)d_in[1];
    const float* mdm  = (const float*)d_in[2];
    float* bow   = (float*)d_out;
    float* codes = (float*)d_out + (size_t)BB * KK;
    float* fT    = codes;            // stage fT in the not-yet-written codes area

    char* ws = (char*)d_ws;
    u16x8* fA     = (u16x8*)(ws + OFF_FA);
    u16x8* fB     = (u16x8*)(ws + OFF_FB);
    float* esq    = (float*)(ws + OFF_ESQ);
    float* pm     = (float*)(ws + OFF_PM);
    float* ps     = (float*)(ws + OFF_PS);
    float* fact   = (float*)(ws + OFF_FACT);
    float* m_a    = (float*)(ws + OFF_MA);
    float* S_a    = (float*)(ws + OFF_SA);
    float* S_sub  = (float*)(ws + OFF_SSUB);
    unsigned* m2u = (unsigned*)(ws + OFF_M2U);
    float* Scand  = (float*)(ws + OFF_SCAND);
    float* iStot  = (float*)(ws + OFF_ISTOT);
    unsigned* cnt = (unsigned*)(ws + OFF_CNT);
    int* cpos     = (int*)(ws + OFF_CPOS);
    float* cl2    = (float*)(ws + OFF_CL2);
    unsigned short* Ebf = (unsigned short*)(ws + OFF_E);

    init_aux<<<36, 256, 0, stream>>>(S_sub, m2u, Scand, cnt);
    prep_A<<<dim3(16, 64), 256, 0, stream>>>(feat, fA, fT);
    prep_B<<<dim3(16, 64), 256, 0, stream>>>(emb, fB);
    rowsumsq<<<KK / 4, 256, 0, stream>>>(emb, esq);
    gemm1<<<4608, 256, 0, stream>>>((const char*)fA, (const char*)fB,
                                    esq, mdm, pm, ps, Ebf);
    comb1<<<36, 256, 0, stream>>>(pm, ps, fact, m_a, S_a);
    detect<<<9216, 256, 0, stream>>>(Ebf, fact, S_sub, cnt, cpos);
    refine1<<<1024, 256, 0, stream>>>(cpos, cnt, fT, emb, esq, mdm, cl2, m2u);
    refine2<<<256, 256, 0, stream>>>(cpos, cl2, cnt, m2u, Scand);
    comb2<<<36, 256, 0, stream>>>(pm, m_a, S_a, S_sub, m2u, Scand, fact, iStot);
    scale_bow<<<(BB * KK) / 4, 256, 0, stream>>>(Ebf, fact, codes, bow);
    scatter<<<256, 256, 0, stream>>>(cpos, cl2, cnt, m2u, iStot, codes, bow);
    bow_norm<<<BB, 256, 0, stream>>>(bow);
}